// Round 10
// baseline (175.127 us; speedup 1.0000x reference)
//
#include <hip/hip_runtime.h>
#include <math.h>

#define NBATCH 4
#define NPTS   8192
#define KNN    8
#define NCH    4096
#define SLICES 16
#define SLEN   512               // candidates per slice-wave
#define NWIN   8                 // windows per slice
#define WLEN   64                // candidates per window
#define PB_OFF 256
#define C2_OFF (PB_OFF + NBATCH * NPTS * 16)   // after 512KB pair buffer

typedef float v2f __attribute__((ext_vector_type(2)));
typedef float v4f __attribute__((ext_vector_type(4)));

__device__ __forceinline__ unsigned umin32(unsigned a, unsigned b) { return a < b ? a : b; }

// single-block insert: 8 instrs, bd pinned via tied "+v", in-place descending
// order reads only pre-block values => depth-1 sorted insert (ascending top-8).
#define INSERT8(bd, key)                                          \
    asm("v_med3_u32 %7, %8, %6, %7\n\t"                           \
        "v_med3_u32 %6, %8, %5, %6\n\t"                           \
        "v_med3_u32 %5, %8, %4, %5\n\t"                           \
        "v_med3_u32 %4, %8, %3, %4\n\t"                           \
        "v_med3_u32 %3, %8, %2, %3\n\t"                           \
        "v_med3_u32 %2, %8, %1, %2\n\t"                           \
        "v_med3_u32 %1, %8, %0, %1\n\t"                           \
        "v_min_u32  %0, %0, %8"                                   \
        : "+v"(bd[0]), "+v"(bd[1]), "+v"(bd[2]), "+v"(bd[3]),     \
          "+v"(bd[4]), "+v"(bd[5]), "+v"(bd[6]), "+v"(bd[7])      \
        : "v"(key))

// points (float3) -> pair-interleaved {x0,x1,y0,y1,z0,z1,|p0|^2,|p1|^2};
// tasks [0,16384) = pred pairs, [16384,18432) = chunk2 pairs; also zeroes acc.
__global__ __launch_bounds__(256) void prep_kernel(const float* __restrict__ pts,
                                                   const float* __restrict__ c2,
                                                   float* __restrict__ pb,
                                                   float* __restrict__ c2p,
                                                   double* __restrict__ acc) {
    const int gi = blockIdx.x * 256 + threadIdx.x;
    if (gi < 8) acc[gi] = 0.0;
    const float* src;
    float* dst;
    int pi;
    if (gi < NBATCH * NPTS / 2) { src = pts; dst = pb; pi = gi; }
    else { src = c2; dst = c2p; pi = gi - NBATCH * NPTS / 2; }
    const float2 u0 = *reinterpret_cast<const float2*>(src + (size_t)pi * 6 + 0);
    const float2 u1 = *reinterpret_cast<const float2*>(src + (size_t)pi * 6 + 2);
    const float2 u2 = *reinterpret_cast<const float2*>(src + (size_t)pi * 6 + 4);
    const float x0 = u0.x, y0 = u0.y, z0 = u1.x;
    const float x1 = u1.y, y1 = u2.x, z1 = u2.y;
    float4* o = reinterpret_cast<float4*>(dst + (size_t)pi * 8);
    o[0] = make_float4(x0, x1, y0, y1);
    o[1] = make_float4(z0, z1, x0 * x0 + y0 * y0 + z0 * z0,
                               x1 * x1 + y1 * y1 + z1 * z1);
}

// Continuity kNN, window-min form: block = 16 slice-waves; every wave holds the
// SAME 64 queries (one per lane), scans its 512-candidate slice as 8 windows of
// 64, keeping only each window's min key (26-bit d2 surrogate | 6-bit local idx).
// Loads go down the VECTOR path (voffset laundered into a VGPR so the compiler
// can't scalarize): uniform-address global_load_dwordx4, HW-broadcast, deeply
// vmcnt-pipelined. Per pair: 4 pk + 2 and_or + 2 min = 8 VALU. Window minima
// re-packed to 19-bit d2 | 13-bit global idx, exact med3 top-8 merge.
__global__ __launch_bounds__(1024, 8) void cont_kernel(const float* __restrict__ pb,
                                                       double* __restrict__ acc) {
    __shared__ unsigned mrg[SLICES][KNN][64];   // 32 KB, lane-consecutive
    const int t    = threadIdx.x;
    const int lane = t & 63;
    const int w    = __builtin_amdgcn_readfirstlane(t >> 6);   // slice id (SGPR)
    const int nqw  = NPTS / 64;
    const int b    = blockIdx.x / nqw;
    const int q0   = (blockIdx.x % nqw) * 64;
    const float* __restrict__ B = pb + (size_t)b * NPTS * 4;

    const int qi = q0 + lane;
    const float* qp = B + (size_t)(qi >> 1) * 8;
    const int e = qi & 1;
    const float qx = qp[0 + e], qy = qp[2 + e], qz = qp[4 + e], qw = qp[6 + e];
    const float qnp = qw + 1e-6f;               // keeps self-key positive
    const v2f qnp2 = {qnp, qnp};
    const v2f m2x2 = {-2.f * qx, -2.f * qx};
    const v2f m2y2 = {-2.f * qy, -2.f * qy};
    const v2f m2z2 = {-2.f * qz, -2.f * qz};
    unsigned vmask;
    asm("v_mov_b32 %0, 0xFFFFFFC0" : "=v"(vmask));   // keep 26 d2 bits in scan keys

    int voff = w * (SLEN * 4);                  // float offset of this wave's slice
    asm("" : "+v"(voff));                       // force divergent => vector loads

    const unsigned jb = (unsigned)(w * SLEN);
    unsigned keyout[NWIN];

#pragma unroll
    for (int wi = 0; wi < NWIN; ++wi) {
        const float* __restrict__ Wp = B + voff + wi * (WLEN * 4);
        unsigned wmA = 0xFFFFFFFFu, wmB = 0xFFFFFFFFu;
#pragma unroll 32
        for (int j = 0; j < WLEN / 2; ++j) {
            const v4f ab = *reinterpret_cast<const v4f*>(Wp + j * 8);      // x0 x1 y0 y1
            const v4f cd = *reinterpret_cast<const v4f*>(Wp + j * 8 + 4);  // z0 z1 w0 w1
            const v2f xp = __builtin_shufflevector(ab, ab, 0, 1);
            const v2f yp = __builtin_shufflevector(ab, ab, 2, 3);
            const v2f zp = __builtin_shufflevector(cd, cd, 0, 1);
            const v2f wp = __builtin_shufflevector(cd, cd, 2, 3);
            v2f s2;
            asm("v_pk_add_f32 %0, %1, %2" : "=v"(s2) : "v"(wp), "v"(qnp2));
            asm("v_pk_fma_f32 %0, %1, %2, %0" : "+v"(s2) : "v"(zp), "v"(m2z2));
            asm("v_pk_fma_f32 %0, %1, %2, %0" : "+v"(s2) : "v"(yp), "v"(m2y2));
            asm("v_pk_fma_f32 %0, %1, %2, %0" : "+v"(s2) : "v"(xp), "v"(m2x2));
            unsigned k0, k1;
            asm("v_and_or_b32 %0, %1, %2, %3"
                : "=v"(k0) : "v"(__float_as_uint(s2.x)), "v"(vmask), "i"(2 * j));
            asm("v_and_or_b32 %0, %1, %2, %3"
                : "=v"(k1) : "v"(__float_as_uint(s2.y)), "v"(vmask), "i"(2 * j + 1));
            wmA = umin32(wmA, k0);
            wmB = umin32(wmB, k1);
        }
        const unsigned wm = umin32(wmA, wmB);
        const unsigned base = jb + (unsigned)(wi * WLEN);   // scalar per window
        keyout[wi] = (wm & 0xFFFFE000u) | base | (wm & 63u);
    }

#pragma unroll
    for (int wi = 0; wi < NWIN; ++wi) mrg[w][wi][lane] = keyout[wi];
    __syncthreads();

    // stage 1: waves 0..3 each merge 4 slices' window minima (self filtered)
    if (w < 4) {
        const unsigned selfidx = (unsigned)qi;
        unsigned best[KNN];
#pragma unroll
        for (int s = 0; s < KNN; ++s) best[s] = 0xFFFFFFFFu;
        for (int sl = 4 * w; sl < 4 * w + 4; ++sl) {
#pragma unroll
            for (int u = 0; u < KNN; ++u) {
                unsigned key = mrg[sl][u][lane];
                key = ((key & 0x1FFFu) == selfidx) ? 0xFFFFFFFFu : key;
                INSERT8(best, key);
            }
        }
#pragma unroll
        for (int s = 0; s < KNN; ++s) mrg[4 * w][s][lane] = best[s];
    }
    __syncthreads();

    // stage 2: wave 0 merges the 4 partials; closed-form deviation sum
    if (w == 0) {
        unsigned best[KNN];
#pragma unroll
        for (int s = 0; s < KNN; ++s) best[s] = 0xFFFFFFFFu;
        for (int g = 0; g < 4; ++g) {
#pragma unroll
            for (int u = 0; u < KNN; ++u) {
                const unsigned key = mrg[4 * g][u][lane];
                INSERT8(best, key);
            }
        }
        float sx = 0.f, sy = 0.f, sz = 0.f, sw = 0.f;
#pragma unroll
        for (int s = 0; s < KNN; ++s) {
            const unsigned n = best[s] & 0x1FFFu;
            const float* np = B + (size_t)(n >> 1) * 8 + (n & 1);
            sx += np[0]; sy += np[2]; sz += np[4]; sw += np[6];
        }
        float ssum = sw - (sx * sx + sy * sy + sz * sz) * (1.f / KNN);
#pragma unroll
        for (int o = 32; o > 0; o >>= 1) ssum += __shfl_down(ssum, o, 64);
        if (lane == 0) atomicAdd(&acc[2], (double)ssum);
    }
}

// Fused aux (512 thr): blocks [0,48) recon MSE (float4), [48,50) percep (float4),
// [50,114) boundary: 64 queries/block (one per lane), 8 waves x 256 c2-pairs,
// vector-path uniform loads (laundered voffset) + packed-fp32 min.
__global__ __launch_bounds__(512) void aux_kernel(const float* __restrict__ a,
                                                  const float* __restrict__ bt,
                                                  const float* __restrict__ a2,
                                                  const float* __restrict__ b2,
                                                  const float* __restrict__ c1,
                                                  const float* __restrict__ c2p,
                                                  double* __restrict__ acc) {
    __shared__ float smem[8 * 64];
    const int t = threadIdx.x;
    const int blk = blockIdx.x;
    if (blk < 50) {
        float s;
        int which;
        if (blk < 48) {
            which = 0;
            const int i = blk * 512 + t;
            const float4 va = reinterpret_cast<const float4*>(a)[i];
            const float4 vb = reinterpret_cast<const float4*>(bt)[i];
            const float dx = va.x - vb.x, dy = va.y - vb.y;
            const float dz = va.z - vb.z, dw = va.w - vb.w;
            s = dx * dx + dy * dy + dz * dz + dw * dw;
        } else {
            which = 1;
            const int i = (blk - 48) * 512 + t;
            const float4 va = reinterpret_cast<const float4*>(a2)[i];
            const float4 vb = reinterpret_cast<const float4*>(b2)[i];
            const float dx = va.x - vb.x, dy = va.y - vb.y;
            const float dz = va.z - vb.z, dw = va.w - vb.w;
            s = dx * dx + dy * dy + dz * dz + dw * dw;
        }
#pragma unroll
        for (int o = 32; o > 0; o >>= 1) s += __shfl_down(s, o, 64);
        if ((t & 63) == 0) smem[t >> 6] = s;
        __syncthreads();
        if (t == 0) {
            float bs = 0.f;
#pragma unroll
            for (int i = 0; i < 8; ++i) bs += smem[i];
            atomicAdd(&acc[which], (double)bs);
        }
    } else {
        const int lane = t & 63;
        const int w8 = __builtin_amdgcn_readfirstlane(t >> 6);   // 0..7
        const int qi = (blk - 50) * 64 + lane;
        const float qx = c1[qi * 3 + 0];
        const float qy = c1[qi * 3 + 1];
        const float qz = c1[qi * 3 + 2];
        const float qn = qx * qx + qy * qy + qz * qz;
        const v2f zero2 = {0.f, 0.f};
        const v2f m2x2 = {-2.f * qx, -2.f * qx};
        const v2f m2y2 = {-2.f * qy, -2.f * qy};
        const v2f m2z2 = {-2.f * qz, -2.f * qz};
        float m = 3.0e38f;
        int voff = w8 * (256 * 8);
        asm("" : "+v"(voff));                   // vector-path uniform loads
        const float* __restrict__ Sp = c2p + voff;
#pragma unroll 16
        for (int j = 0; j < 256; ++j) {
            const v4f ab = *reinterpret_cast<const v4f*>(Sp + j * 8);
            const v4f cd = *reinterpret_cast<const v4f*>(Sp + j * 8 + 4);
            const v2f xp = __builtin_shufflevector(ab, ab, 0, 1);
            const v2f yp = __builtin_shufflevector(ab, ab, 2, 3);
            const v2f zp = __builtin_shufflevector(cd, cd, 0, 1);
            const v2f wp = __builtin_shufflevector(cd, cd, 2, 3);
            v2f s2;
            asm("v_pk_add_f32 %0, %1, %2" : "=v"(s2) : "v"(wp), "v"(zero2));
            asm("v_pk_fma_f32 %0, %1, %2, %0" : "+v"(s2) : "v"(zp), "v"(m2z2));
            asm("v_pk_fma_f32 %0, %1, %2, %0" : "+v"(s2) : "v"(yp), "v"(m2y2));
            asm("v_pk_fma_f32 %0, %1, %2, %0" : "+v"(s2) : "v"(xp), "v"(m2x2));
            m = fminf(m, fminf(s2.x, s2.y));
        }
        smem[w8 * 64 + lane] = m;
        __syncthreads();
        if (w8 == 0) {
            float mm = smem[lane];
#pragma unroll
            for (int s = 1; s < 8; ++s) mm = fminf(mm, smem[s * 64 + lane]);
            const float d = sqrtf(fmaxf(mm + qn, 0.f));
            const bool in = d < 0.1f;
            float sc = in ? d : 0.f;
            float sn = in ? 1.f : 0.f;
#pragma unroll
            for (int o = 32; o > 0; o >>= 1) {
                sc += __shfl_down(sc, o, 64);
                sn += __shfl_down(sn, o, 64);
            }
            if (lane == 0) {
                atomicAdd(&acc[3], (double)sc);
                atomicAdd(&acc[4], (double)sn);
            }
        }
    }
}

__global__ void fin_kernel(const double* __restrict__ acc, float* __restrict__ out) {
    if (threadIdx.x == 0) {
        const double recon  = acc[0] / (double)(NBATCH * NPTS * 3);
        const double percep = acc[1] / 4096.0;
        const double cont   = acc[2] / (double)(NBATCH * NPTS * KNN);
        const double cnt    = acc[4];
        const double bnd    = (cnt > 0.0) ? acc[3] / ((cnt > 1.0) ? cnt : 1.0) : 0.0;
        const double total  = 1.0 * recon + 0.5 * percep + 0.5 * cont + 1.0 * bnd;
        out[0] = (float)recon;
        out[1] = (float)percep;
        out[2] = (float)cont;
        out[3] = (float)bnd;
        out[4] = (float)total;
    }
}

extern "C" void kernel_launch(void* const* d_in, const int* in_sizes, int n_in,
                              void* d_out, int out_size, void* d_ws, size_t ws_size,
                              hipStream_t stream) {
    const float* pred = (const float*)d_in[0];
    const float* targ = (const float*)d_in[1];
    const float* pf   = (const float*)d_in[2];
    const float* tf   = (const float*)d_in[3];
    const float* c1   = (const float*)d_in[4];
    const float* c2   = (const float*)d_in[5];
    float* out  = (float*)d_out;
    double* acc = (double*)d_ws;
    float* pb   = (float*)((char*)d_ws + PB_OFF);
    float* c2p  = (float*)((char*)d_ws + C2_OFF);

    hipLaunchKernelGGL(prep_kernel, dim3((NBATCH * NPTS / 2 + NCH / 2) / 256), dim3(256),
                       0, stream, pred, c2, pb, c2p, acc);
    hipLaunchKernelGGL(cont_kernel, dim3(NBATCH * (NPTS / 64)), dim3(1024), 0, stream,
                       pb, acc);
    hipLaunchKernelGGL(aux_kernel, dim3(114), dim3(512), 0, stream,
                       pred, targ, pf, tf, c1, c2p, acc);
    hipLaunchKernelGGL(fin_kernel, dim3(1), dim3(64), 0, stream, acc, out);
}

// Round 11
// 67.765 us; speedup vs baseline: 2.5843x; 2.5843x over previous
//
#include <hip/hip_runtime.h>
#include <math.h>

#define NBATCH 4
#define NPTS   8192
#define KNN    8
#define NCH    4096
#define SLICES 16
#define SLEN   512               // candidates per slice-wave
#define NWIN   8                 // windows per slice
#define WLEN   64                // candidates per window
#define PB_OFF 256
#define C2_OFF (PB_OFF + NBATCH * NPTS * 16)   // after 512KB pair buffer

typedef float v2f __attribute__((ext_vector_type(2)));

__device__ __forceinline__ unsigned umin32(unsigned a, unsigned b) { return a < b ? a : b; }

// single-block insert: 8 instrs, bd pinned via tied "+v", in-place descending
// order reads only pre-block values => depth-1 sorted insert (ascending top-8).
// Used ONLY in the merge phases (not the hot scan loop).
#define INSERT8(bd, key)                                          \
    asm("v_med3_u32 %7, %8, %6, %7\n\t"                           \
        "v_med3_u32 %6, %8, %5, %6\n\t"                           \
        "v_med3_u32 %5, %8, %4, %5\n\t"                           \
        "v_med3_u32 %4, %8, %3, %4\n\t"                           \
        "v_med3_u32 %3, %8, %2, %3\n\t"                           \
        "v_med3_u32 %2, %8, %1, %2\n\t"                           \
        "v_med3_u32 %1, %8, %0, %1\n\t"                           \
        "v_min_u32  %0, %0, %8"                                   \
        : "+v"(bd[0]), "+v"(bd[1]), "+v"(bd[2]), "+v"(bd[3]),     \
          "+v"(bd[4]), "+v"(bd[5]), "+v"(bd[6]), "+v"(bd[7])      \
        : "v"(key))

// points (float3) -> pair-interleaved {x0,x1,y0,y1,z0,z1,|p0|^2,|p1|^2};
// tasks [0,16384) = pred pairs, [16384,18432) = chunk2 pairs; also zeroes acc.
__global__ __launch_bounds__(256) void prep_kernel(const float* __restrict__ pts,
                                                   const float* __restrict__ c2,
                                                   float* __restrict__ pb,
                                                   float* __restrict__ c2p,
                                                   double* __restrict__ acc) {
    const int gi = blockIdx.x * 256 + threadIdx.x;
    if (gi < 8) acc[gi] = 0.0;
    const float* src;
    float* dst;
    int pi;
    if (gi < NBATCH * NPTS / 2) { src = pts; dst = pb; pi = gi; }
    else { src = c2; dst = c2p; pi = gi - NBATCH * NPTS / 2; }
    const float2 u0 = *reinterpret_cast<const float2*>(src + (size_t)pi * 6 + 0);
    const float2 u1 = *reinterpret_cast<const float2*>(src + (size_t)pi * 6 + 2);
    const float2 u2 = *reinterpret_cast<const float2*>(src + (size_t)pi * 6 + 4);
    const float x0 = u0.x, y0 = u0.y, z0 = u1.x;
    const float x1 = u1.y, y1 = u2.x, z1 = u2.y;
    float4* o = reinterpret_cast<float4*>(dst + (size_t)pi * 8);
    o[0] = make_float4(x0, x1, y0, y1);
    o[1] = make_float4(z0, z1, x0 * x0 + y0 * y0 + z0 * z0,
                               x1 * x1 + y1 * y1 + z1 * z1);
}

// Continuity kNN, window-min form: block = 16 slice-waves; every wave holds the
// SAME 64 queries (one per lane), scans its 512-candidate slice as 8 windows of
// 64 via wave-uniform s_loads (plain C so the compiler software-pipelines the
// scalar stream freely — r7 showed 95% VALUBusy this way). Keeps each window's
// min key (26-bit d2 surrogate | 6-bit local idx); window minima re-packed to
// 19-bit d2 | 13-bit global idx, exact med3 top-8 merge, self filtered there.
__global__ __launch_bounds__(1024, 8) void cont_kernel(const float* __restrict__ pb,
                                                       double* __restrict__ acc) {
    __shared__ unsigned mrg[SLICES][KNN][64];   // 32 KB, lane-consecutive
    const int t    = threadIdx.x;
    const int lane = t & 63;
    const int w    = __builtin_amdgcn_readfirstlane(t >> 6);   // slice id (SGPR)
    const int nqw  = NPTS / 64;
    const int b    = blockIdx.x / nqw;
    const int q0   = (blockIdx.x % nqw) * 64;
    const float* __restrict__ B = pb + (size_t)b * NPTS * 4;

    const int qi = q0 + lane;
    const float* qp = B + (size_t)(qi >> 1) * 8;
    const int e = qi & 1;
    const float qx = qp[0 + e], qy = qp[2 + e], qz = qp[4 + e], qw = qp[6 + e];
    const float qnp = qw + 1e-6f;               // keeps self-key positive
    const v2f qnp2 = {qnp, qnp};
    const v2f m2x2 = {-2.f * qx, -2.f * qx};
    const v2f m2y2 = {-2.f * qy, -2.f * qy};
    const v2f m2z2 = {-2.f * qz, -2.f * qz};

    const float* __restrict__ Sp = B + (size_t)w * SLEN * 4;
    const unsigned jb = (unsigned)(w * SLEN);
    unsigned keyout[NWIN];

#pragma unroll
    for (int wi = 0; wi < NWIN; ++wi) {
        const float* __restrict__ Wp = Sp + wi * (WLEN * 4);
        unsigned wmA = 0xFFFFFFFFu, wmB = 0xFFFFFFFFu;
#pragma unroll
        for (int j = 0; j < WLEN / 2; ++j) {
            const float4 ab = *reinterpret_cast<const float4*>(Wp + j * 8);      // x0 x1 y0 y1
            const float4 cd = *reinterpret_cast<const float4*>(Wp + j * 8 + 4);  // z0 z1 w0 w1
            const v2f xp = {ab.x, ab.y}, yp = {ab.z, ab.w};
            const v2f zp = {cd.x, cd.y}, wp = {cd.z, cd.w};
            v2f s2 = wp + qnp2;
            s2 = __builtin_elementwise_fma(zp, m2z2, s2);
            s2 = __builtin_elementwise_fma(yp, m2y2, s2);
            s2 = __builtin_elementwise_fma(xp, m2x2, s2);
            const unsigned k0 = (__float_as_uint(s2.x) & 0xFFFFFFC0u) | (unsigned)(2 * j);
            const unsigned k1 = (__float_as_uint(s2.y) & 0xFFFFFFC0u) | (unsigned)(2 * j + 1);
            wmA = umin32(wmA, k0);
            wmB = umin32(wmB, k1);
        }
        const unsigned wm = umin32(wmA, wmB);
        const unsigned base = jb + (unsigned)(wi * WLEN);   // scalar per window
        keyout[wi] = (wm & 0xFFFFE000u) | base | (wm & 63u);
    }

#pragma unroll
    for (int wi = 0; wi < NWIN; ++wi) mrg[w][wi][lane] = keyout[wi];
    __syncthreads();

    // stage 1: waves 0..3 each merge 4 slices' window minima (self filtered)
    if (w < 4) {
        const unsigned selfidx = (unsigned)qi;
        unsigned best[KNN];
#pragma unroll
        for (int s = 0; s < KNN; ++s) best[s] = 0xFFFFFFFFu;
        for (int sl = 4 * w; sl < 4 * w + 4; ++sl) {
#pragma unroll
            for (int u = 0; u < KNN; ++u) {
                unsigned key = mrg[sl][u][lane];
                key = ((key & 0x1FFFu) == selfidx) ? 0xFFFFFFFFu : key;
                INSERT8(best, key);
            }
        }
#pragma unroll
        for (int s = 0; s < KNN; ++s) mrg[4 * w][s][lane] = best[s];
    }
    __syncthreads();

    // stage 2: wave 0 merges the 4 partials; closed-form deviation sum
    if (w == 0) {
        unsigned best[KNN];
#pragma unroll
        for (int s = 0; s < KNN; ++s) best[s] = 0xFFFFFFFFu;
        for (int g = 0; g < 4; ++g) {
#pragma unroll
            for (int u = 0; u < KNN; ++u) {
                const unsigned key = mrg[4 * g][u][lane];
                INSERT8(best, key);
            }
        }
        float sx = 0.f, sy = 0.f, sz = 0.f, sw = 0.f;
#pragma unroll
        for (int s = 0; s < KNN; ++s) {
            const unsigned n = best[s] & 0x1FFFu;
            const float* np = B + (size_t)(n >> 1) * 8 + (n & 1);
            sx += np[0]; sy += np[2]; sz += np[4]; sw += np[6];
        }
        float ssum = sw - (sx * sx + sy * sy + sz * sz) * (1.f / KNN);
#pragma unroll
        for (int o = 32; o > 0; o >>= 1) ssum += __shfl_down(ssum, o, 64);
        if (lane == 0) atomicAdd(&acc[2], (double)ssum);
    }
}

// Fused aux (512 thr): blocks [0,48) recon MSE (float4), [48,50) percep (float4),
// [50,114) boundary: 64 queries/block (one per lane), 8 waves x 256 c2-pairs via
// wave-uniform s_loads (plain C) + packed min of |p|^2-2p.q; |q|^2 added once.
__global__ __launch_bounds__(512) void aux_kernel(const float* __restrict__ a,
                                                  const float* __restrict__ bt,
                                                  const float* __restrict__ a2,
                                                  const float* __restrict__ b2,
                                                  const float* __restrict__ c1,
                                                  const float* __restrict__ c2p,
                                                  double* __restrict__ acc) {
    __shared__ float smem[8 * 64];
    const int t = threadIdx.x;
    const int blk = blockIdx.x;
    if (blk < 50) {
        float s;
        int which;
        if (blk < 48) {
            which = 0;
            const int i = blk * 512 + t;
            const float4 va = reinterpret_cast<const float4*>(a)[i];
            const float4 vb = reinterpret_cast<const float4*>(bt)[i];
            const float dx = va.x - vb.x, dy = va.y - vb.y;
            const float dz = va.z - vb.z, dw = va.w - vb.w;
            s = dx * dx + dy * dy + dz * dz + dw * dw;
        } else {
            which = 1;
            const int i = (blk - 48) * 512 + t;
            const float4 va = reinterpret_cast<const float4*>(a2)[i];
            const float4 vb = reinterpret_cast<const float4*>(b2)[i];
            const float dx = va.x - vb.x, dy = va.y - vb.y;
            const float dz = va.z - vb.z, dw = va.w - vb.w;
            s = dx * dx + dy * dy + dz * dz + dw * dw;
        }
#pragma unroll
        for (int o = 32; o > 0; o >>= 1) s += __shfl_down(s, o, 64);
        if ((t & 63) == 0) smem[t >> 6] = s;
        __syncthreads();
        if (t == 0) {
            float bs = 0.f;
#pragma unroll
            for (int i = 0; i < 8; ++i) bs += smem[i];
            atomicAdd(&acc[which], (double)bs);
        }
    } else {
        const int lane = t & 63;
        const int w8 = __builtin_amdgcn_readfirstlane(t >> 6);   // 0..7
        const int qi = (blk - 50) * 64 + lane;
        const float qx = c1[qi * 3 + 0];
        const float qy = c1[qi * 3 + 1];
        const float qz = c1[qi * 3 + 2];
        const float qn = qx * qx + qy * qy + qz * qz;
        const v2f m2x2 = {-2.f * qx, -2.f * qx};
        const v2f m2y2 = {-2.f * qy, -2.f * qy};
        const v2f m2z2 = {-2.f * qz, -2.f * qz};
        float m = 3.0e38f;
        const float* __restrict__ Sp = c2p + (size_t)w8 * 256 * 8;   // 256 pairs
#pragma unroll 16
        for (int j = 0; j < 256; ++j) {
            const float4 ab = *reinterpret_cast<const float4*>(Sp + j * 8);
            const float4 cd = *reinterpret_cast<const float4*>(Sp + j * 8 + 4);
            const v2f xp = {ab.x, ab.y}, yp = {ab.z, ab.w};
            const v2f zp = {cd.x, cd.y};
            v2f s2 = {cd.z, cd.w};
            s2 = __builtin_elementwise_fma(zp, m2z2, s2);
            s2 = __builtin_elementwise_fma(yp, m2y2, s2);
            s2 = __builtin_elementwise_fma(xp, m2x2, s2);
            m = fminf(m, fminf(s2.x, s2.y));
        }
        smem[w8 * 64 + lane] = m;
        __syncthreads();
        if (w8 == 0) {
            float mm = smem[lane];
#pragma unroll
            for (int s = 1; s < 8; ++s) mm = fminf(mm, smem[s * 64 + lane]);
            const float d = sqrtf(fmaxf(mm + qn, 0.f));
            const bool in = d < 0.1f;
            float sc = in ? d : 0.f;
            float sn = in ? 1.f : 0.f;
#pragma unroll
            for (int o = 32; o > 0; o >>= 1) {
                sc += __shfl_down(sc, o, 64);
                sn += __shfl_down(sn, o, 64);
            }
            if (lane == 0) {
                atomicAdd(&acc[3], (double)sc);
                atomicAdd(&acc[4], (double)sn);
            }
        }
    }
}

__global__ void fin_kernel(const double* __restrict__ acc, float* __restrict__ out) {
    if (threadIdx.x == 0) {
        const double recon  = acc[0] / (double)(NBATCH * NPTS * 3);
        const double percep = acc[1] / 4096.0;
        const double cont   = acc[2] / (double)(NBATCH * NPTS * KNN);
        const double cnt    = acc[4];
        const double bnd    = (cnt > 0.0) ? acc[3] / ((cnt > 1.0) ? cnt : 1.0) : 0.0;
        const double total  = 1.0 * recon + 0.5 * percep + 0.5 * cont + 1.0 * bnd;
        out[0] = (float)recon;
        out[1] = (float)percep;
        out[2] = (float)cont;
        out[3] = (float)bnd;
        out[4] = (float)total;
    }
}

extern "C" void kernel_launch(void* const* d_in, const int* in_sizes, int n_in,
                              void* d_out, int out_size, void* d_ws, size_t ws_size,
                              hipStream_t stream) {
    const float* pred = (const float*)d_in[0];
    const float* targ = (const float*)d_in[1];
    const float* pf   = (const float*)d_in[2];
    const float* tf   = (const float*)d_in[3];
    const float* c1   = (const float*)d_in[4];
    const float* c2   = (const float*)d_in[5];
    float* out  = (float*)d_out;
    double* acc = (double*)d_ws;
    float* pb   = (float*)((char*)d_ws + PB_OFF);
    float* c2p  = (float*)((char*)d_ws + C2_OFF);

    hipLaunchKernelGGL(prep_kernel, dim3((NBATCH * NPTS / 2 + NCH / 2) / 256), dim3(256),
                       0, stream, pred, c2, pb, c2p, acc);
    hipLaunchKernelGGL(cont_kernel, dim3(NBATCH * (NPTS / 64)), dim3(1024), 0, stream,
                       pb, acc);
    hipLaunchKernelGGL(aux_kernel, dim3(114), dim3(512), 0, stream,
                       pred, targ, pf, tf, c1, c2p, acc);
    hipLaunchKernelGGL(fin_kernel, dim3(1), dim3(64), 0, stream, acc, out);
}